// Round 7
// baseline (536.459 us; speedup 1.0000x reference)
//
#include <hip/hip_runtime.h>
#include <math.h>

#define NROWS 65536
#define D 256
#define K 1024

// d_out offsets (floats)
#define OFF_Q     0
#define OFF_LOSS  16777216
#define OFF_IDX   16777217
#define OFF_CS    16842753
#define OFF_EMAW  16843777
#define OFF_UPD   17105921

// ws offsets (bytes)
#define WS_HIST     0          // 1024 int  (memset)
#define WS_OFFS     4096       // 1024 int
#define WS_CURS     8192       // 1024 int
#define WS_IDX      12288      // 65536 int
#define WS_ROWIDS   274432     // 65536 int
#define WS_SQX      536576     // 65536 f32
#define WS_SQE      798720     // 1024 f32
#define WS_DW       802816     // 262144 f32
#define WS_LOSSP    1851392    // 1024 double (ends 1859584)

__device__ __forceinline__ void gload16(const void* g, void* l) {
    __builtin_amdgcn_global_load_lds(
        (const __attribute__((address_space(1))) void*)g,
        (__attribute__((address_space(3))) void*)l, 16, 0, 0);
}

// ---------------- K0: row sum-of-squares, numpy AVX512 pairwise order ----------------
__global__ __launch_bounds__(256) void k_sq(const float* __restrict__ a_,
                                            float* __restrict__ dst, int n)
{
#pragma clang fp contract(off)
    int r = blockIdx.x * 256 + threadIdx.x;
    if (r >= n) return;
    const float4* a4 = (const float4*)(a_ + (size_t)r * 256);
    float h[2];
#pragma unroll
    for (int hh = 0; hh < 2; ++hh) {
        float p[4][16];
#pragma unroll
        for (int pr = 0; pr < 4; ++pr) {      // pair (2pr, 2pr+1) of 16-float chunks
#pragma unroll
            for (int m = 0; m < 4; ++m) {
                float4 u = a4[hh * 32 + (2 * pr) * 4 + m];
                float4 v = a4[hh * 32 + (2 * pr + 1) * 4 + m];
                p[pr][4 * m + 0] = u.x * u.x + v.x * v.x;
                p[pr][4 * m + 1] = u.y * u.y + v.y * v.y;
                p[pr][4 * m + 2] = u.z * u.z + v.z * v.z;
                p[pr][4 * m + 3] = u.w * u.w + v.w * v.w;
            }
        }
        float V[16];
#pragma unroll
        for (int l = 0; l < 16; ++l) V[l] = (p[0][l] + p[1][l]) + (p[2][l] + p[3][l]);
        float t[8];
#pragma unroll
        for (int l = 0; l < 8; ++l) t[l] = V[l] + V[l + 8];
        float u2[4];
#pragma unroll
        for (int l = 0; l < 4; ++l) u2[l] = t[l] + t[l + 4];
        h[hh] = (u2[0] + u2[2]) + (u2[1] + u2[3]);
    }
    dst[r] = h[0] + h[1];
}

// ---------------- K1: tiled f32 GEMM-argmin, numpy/BLAS-exact arithmetic ----------------
// 128 rows x 1024 codes per block (4 ct-tiles of 256 codes); acc[8][16]/thread.
// amdgpu_waves_per_eu(2,2): force 256-VGPR budget so acc stays in arch VGPRs
// (round 6: VGPR_Count=124 -> AGPR-split accumulator cost ~2.2 cyc/FMA in
//  v_accvgpr traffic; grid = 2 blocks/CU anyway, so 2 waves/EU loses nothing).
// Per (row,code): single f32 accumulator, fmaf over k ascending (BLAS order).
// dist = (sqx - 2*dot) + sqe (two separate f32 roundings); argmin = lex-min(value,index).
__global__ __attribute__((amdgpu_flat_work_group_size(256, 256)))
__attribute__((amdgpu_waves_per_eu(2, 2))) void k_argmin(
    const float* __restrict__ x, const float* __restrict__ ew,
    const float* __restrict__ sqx, const float* __restrict__ sqe,
    int* __restrict__ idx_out, float* __restrict__ idxf_out,
    int* __restrict__ hist)
{
#pragma clang fp contract(off)
    __shared__ __align__(16) float xs[128][32];   // 16 KB
    __shared__ __align__(16) float es[256][32];   // 32 KB
    const int tid = threadIdx.x;
    const int w = tid >> 6, l = tid & 63;
    const int tx = tid & 15, ty = tid >> 4;
    const int row0 = blockIdx.x * 128;
    const int lr = l >> 3;      // sub-row within a 1KB issue
    const int lg = l & 7;       // stored 16B-group within row

    float sxv[8];
#pragma unroll
    for (int i = 0; i < 8; ++i) sxv[i] = sqx[row0 + ty + 16 * i];

    float best1[8]; int bidx[8];
#pragma unroll
    for (int i = 0; i < 8; ++i) { best1[i] = 3.4e38f; bidx[i] = 0x7fffffff; }

#pragma unroll 1
    for (int ct = 0; ct < 4; ++ct) {
        float acc[8][16];
#pragma unroll
        for (int i = 0; i < 8; ++i)
#pragma unroll
            for (int j = 0; j < 16; ++j) acc[i][j] = 0.f;

#pragma unroll 1
        for (int dc = 0; dc < 8; ++dc) {
            __syncthreads();
            // stage x tile: 128 rows x 32 d = 16KB, 16 issues (4/wave)
#pragma unroll
            for (int q4 = 0; q4 < 4; ++q4) {
                const int q = w + 4 * q4;
                const int r = q * 8 + lr;
                const int g = lg ^ (r & 7);
                gload16(&x[(size_t)(row0 + r) * 256 + dc * 32 + 4 * g], &xs[q * 8][0]);
            }
            // stage e tile: 256 codes x 32 d = 32KB, 32 issues (8/wave)
#pragma unroll
            for (int q8 = 0; q8 < 8; ++q8) {
                const int q = w + 4 * q8;
                const int c = q * 8 + lr;
                const int g = lg ^ (c & 7);
                gload16(&ew[(size_t)(ct * 256 + c) * 256 + dc * 32 + 4 * g], &es[q * 8][0]);
            }
            __syncthreads();
#pragma unroll 1
            for (int dq = 0; dq < 8; ++dq) {
                float4 xa[8];
#pragma unroll
                for (int i = 0; i < 8; ++i) {
                    const int r = ty + 16 * i;
                    xa[i] = *(const float4*)&xs[r][4 * (dq ^ (r & 7))];
                }
#pragma unroll
                for (int j = 0; j < 16; ++j) {
                    const int c = 16 * j + tx;
                    const float4 ev = *(const float4*)&es[c][4 * (dq ^ (c & 7))];
#pragma unroll
                    for (int i = 0; i < 8; ++i) {
                        acc[i][j] = __builtin_fmaf(xa[i].x, ev.x, acc[i][j]);
                        acc[i][j] = __builtin_fmaf(xa[i].y, ev.y, acc[i][j]);
                        acc[i][j] = __builtin_fmaf(xa[i].z, ev.z, acc[i][j]);
                        acc[i][j] = __builtin_fmaf(xa[i].w, ev.w, acc[i][j]);
                    }
                }
            }
        }
        // epilogue for this ct: distances + lex-min
#pragma unroll
        for (int i = 0; i < 8; ++i) {
            float v1 = 3.4e38f; int i1 = 0x7fffffff;
#pragma unroll
            for (int j = 0; j < 16; ++j) {
                const int c = ct * 256 + 16 * j + tx;
                float t = sxv[i] - 2.0f * acc[i][j];   // one rounding (2*acc exact)
                float s = t + sqe[c];                  // second rounding (numpy order)
                if (s < v1 || (s == v1 && c < i1)) { v1 = s; i1 = c; }
            }
#pragma unroll
            for (int m = 1; m < 16; m <<= 1) {
                float o1 = __shfl_xor(v1, m);
                int    oi = __shfl_xor(i1, m);
                if (o1 < v1 || (o1 == v1 && oi < i1)) { v1 = o1; i1 = oi; }
            }
            if (v1 < best1[i] || (v1 == best1[i] && i1 < bidx[i])) {
                best1[i] = v1; bidx[i] = i1;
            }
        }
    }
    if (tx == 0) {
#pragma unroll
        for (int i = 0; i < 8; ++i) {
            const int row = row0 + ty + 16 * i;
            idx_out[row] = bidx[i];
            idxf_out[row] = (float)bidx[i];
            atomicAdd(&hist[bidx[i]], 1);
        }
    }
}

// ---------------- K2: prefix sum of histogram -> offsets + cursors ----------------
__global__ __launch_bounds__(1024) void k_prefix(
    const int* __restrict__ hist, int* __restrict__ offs, int* __restrict__ curs)
{
    __shared__ int tmp[1024];
    const int tid = threadIdx.x;
    const int h = hist[tid];
    tmp[tid] = h;
    __syncthreads();
    for (int off = 1; off < 1024; off <<= 1) {
        int v = (tid >= off) ? tmp[tid - off] : 0;
        __syncthreads();
        tmp[tid] += v;
        __syncthreads();
    }
    int ex = tmp[tid] - h;   // exclusive
    offs[tid] = ex;
    curs[tid] = ex;
}

// ---------------- K3: fill row-id bins ----------------
__global__ __launch_bounds__(256) void k_fill(
    const int* __restrict__ idx_in, int* __restrict__ curs, int* __restrict__ rowids)
{
    int r = blockIdx.x * 256 + threadIdx.x;
    int c = idx_in[r];
    int slot = atomicAdd(&curs[c], 1);
    rowids[slot] = r;
}

// ---------------- K4: per-code dw + quantized gather-write + loss (atomic-free) ----------------
__global__ __launch_bounds__(256) void k_dw(
    const float* __restrict__ x, const float* __restrict__ ew,
    const int* __restrict__ hist, const int* __restrict__ offs,
    const int* __restrict__ rowids,
    float* __restrict__ q_out, float* __restrict__ dw, double* __restrict__ lossp)
{
    const int c = blockIdx.x;
    const int tid = threadIdx.x;          // == d
    const int n = hist[c];
    const int base = offs[c];
    const float ev = ew[(size_t)c * 256 + tid];
    float acc = 0.f;
    float lsum = 0.f;
    for (int i = 0; i < n; ++i) {
        int row = rowids[base + i];
        float xv = x[(size_t)row * 256 + tid];
        q_out[(size_t)row * 256 + tid] = ev;
        acc += xv;
        float df = ev - xv;
        lsum += df * df;
    }
    dw[(size_t)c * 256 + tid] = acc;
    const int lane = tid & 63, wid = tid >> 6;
    __shared__ float wsum[4];
#pragma unroll
    for (int m = 1; m < 64; m <<= 1) lsum += __shfl_xor(lsum, m);
    if (lane == 0) wsum[wid] = lsum;
    __syncthreads();
    if (tid == 0)
        lossp[c] = (double)wsum[0] + wsum[1] + wsum[2] + wsum[3];
}

// ---------------- K5: finalize new_cs (+ n) and loss ----------------
__global__ __launch_bounds__(1024) void k_finalize(
    const float* __restrict__ ema_cs, const int* __restrict__ hist,
    const double* __restrict__ lossp, float* __restrict__ out)
{
    __shared__ double red[1024];
    const int tid = threadIdx.x;
    float raw = ema_cs[tid] * 0.99f + 0.01f * (float)hist[tid];
    red[tid] = (double)raw;
    __syncthreads();
    for (int s = 512; s > 0; s >>= 1) {
        if (tid < s) red[tid] += red[tid + s];
        __syncthreads();
    }
    double n = red[0];
    __syncthreads();
    float csn = (raw + 1e-5f) * (float)(n / (n + 1024.0 * 1e-5));
    out[OFF_CS + tid] = csn;
    red[tid] = lossp[tid];
    __syncthreads();
    for (int s = 512; s > 0; s >>= 1) {
        if (tid < s) red[tid] += red[tid + s];
        __syncthreads();
    }
    if (tid == 0) out[OFF_LOSS] = (float)(red[0] * 1.25 / 16777216.0);
}

// ---------------- K6: new_ema_w + updated_embed ----------------
__global__ __launch_bounds__(256) void k_ema(
    const float* __restrict__ ema_w, const float* __restrict__ dw,
    const float* __restrict__ cs_out, float* __restrict__ out)
{
    int id = blockIdx.x * 256 + threadIdx.x;   // 0..262143
    int k = id >> 8;
    float nw = ema_w[id] * 0.99f + 0.01f * dw[id];
    out[OFF_EMAW + id] = nw;
    out[OFF_UPD + id] = nw / cs_out[k];
}

extern "C" void kernel_launch(void* const* d_in, const int* in_sizes, int n_in,
                              void* d_out, int out_size, void* d_ws, size_t ws_size,
                              hipStream_t stream)
{
    const float* x      = (const float*)d_in[0];
    const float* ew     = (const float*)d_in[1];
    const float* ema_cs = (const float*)d_in[2];
    const float* ema_w  = (const float*)d_in[3];
    float* out = (float*)d_out;
    char* ws = (char*)d_ws;

    int*    hist    = (int*)(ws + WS_HIST);
    int*    offs    = (int*)(ws + WS_OFFS);
    int*    curs    = (int*)(ws + WS_CURS);
    int*    idxi    = (int*)(ws + WS_IDX);
    int*    rowids  = (int*)(ws + WS_ROWIDS);
    float*  sqx     = (float*)(ws + WS_SQX);
    float*  sqe     = (float*)(ws + WS_SQE);
    float*  dw      = (float*)(ws + WS_DW);
    double* lossp   = (double*)(ws + WS_LOSSP);

    hipMemsetAsync(hist, 0, 4096, stream);
    hipLaunchKernelGGL(k_sq, dim3(NROWS / 256), dim3(256), 0, stream, x, sqx, NROWS);
    hipLaunchKernelGGL(k_sq, dim3(K / 256), dim3(256), 0, stream, ew, sqe, K);
    hipLaunchKernelGGL(k_argmin, dim3(NROWS / 128), dim3(256), 0, stream,
                       x, ew, sqx, sqe, idxi, out + OFF_IDX, hist);
    hipLaunchKernelGGL(k_prefix, dim3(1), dim3(1024), 0, stream, hist, offs, curs);
    hipLaunchKernelGGL(k_fill, dim3(NROWS / 256), dim3(256), 0, stream,
                       idxi, curs, rowids);
    hipLaunchKernelGGL(k_dw, dim3(K), dim3(256), 0, stream,
                       x, ew, hist, offs, rowids, out + OFF_Q, dw, lossp);
    hipLaunchKernelGGL(k_finalize, dim3(1), dim3(1024), 0, stream,
                       ema_cs, hist, lossp, out);
    hipLaunchKernelGGL(k_ema, dim3(1024), dim3(256), 0, stream,
                       ema_w, dw, out + OFF_CS, out);
}

// Round 9
// 453.039 us; speedup vs baseline: 1.1841x; 1.1841x over previous
//
#include <hip/hip_runtime.h>
#include <math.h>

#define NROWS 65536
#define D 256
#define K 1024
#define CAP 16
#define EPS 2e-3f

// d_out offsets (floats)
#define OFF_Q     0
#define OFF_LOSS  16777216
#define OFF_IDX   16777217
#define OFF_CS    16842753
#define OFF_EMAW  16843777
#define OFF_UPD   17105921

// ws offsets (bytes)
#define WS_HIST     0          // 1024 int   (memset)
#define WS_CNT      4096       // 65536 int  (memset)
#define WS_OFFS     266240     // 1024 int
#define WS_CURS     270336     // 1024 int
#define WS_IDX      274432     // 65536 int
#define WS_ROWIDS   536576     // 65536 int
#define WS_SQX      798720     // 65536 f32
#define WS_SQE      1060864    // 1024 f32
#define WS_DW       1064960    // 262144 f32
#define WS_LOSSP    2113536    // 1024 double
#define WS_EBT      2121728    // 8*1024*32 ushort (bf16, k-chunk-major)
#define WS_CAND     2646016    // 65536*16 int  (ends 6840320)

typedef __attribute__((ext_vector_type(8))) short short8;
typedef __attribute__((ext_vector_type(8))) unsigned short ushort8;
typedef __attribute__((ext_vector_type(4))) float f32x4;

__device__ __forceinline__ unsigned short f2b(float f) {   // RNE f32->bf16
    unsigned u = __builtin_bit_cast(unsigned, f);
    return (unsigned short)((u + 0x7fffu + ((u >> 16) & 1u)) >> 16);
}

// ---------------- K0: row sum-of-squares, numpy AVX512 pairwise order ----------------
__global__ __launch_bounds__(256) void k_sq(const float* __restrict__ a_,
                                            float* __restrict__ dst, int n)
{
#pragma clang fp contract(off)
    int r = blockIdx.x * 256 + threadIdx.x;
    if (r >= n) return;
    const float4* a4 = (const float4*)(a_ + (size_t)r * 256);
    float h[2];
#pragma unroll
    for (int hh = 0; hh < 2; ++hh) {
        float p[4][16];
#pragma unroll
        for (int pr = 0; pr < 4; ++pr) {
#pragma unroll
            for (int m = 0; m < 4; ++m) {
                float4 u = a4[hh * 32 + (2 * pr) * 4 + m];
                float4 v = a4[hh * 32 + (2 * pr + 1) * 4 + m];
                p[pr][4 * m + 0] = u.x * u.x + v.x * v.x;
                p[pr][4 * m + 1] = u.y * u.y + v.y * v.y;
                p[pr][4 * m + 2] = u.z * u.z + v.z * v.z;
                p[pr][4 * m + 3] = u.w * u.w + v.w * v.w;
            }
        }
        float V[16];
#pragma unroll
        for (int l = 0; l < 16; ++l) V[l] = (p[0][l] + p[1][l]) + (p[2][l] + p[3][l]);
        float t[8];
#pragma unroll
        for (int l = 0; l < 8; ++l) t[l] = V[l] + V[l + 8];
        float u2[4];
#pragma unroll
        for (int l = 0; l < 4; ++l) u2[l] = t[l] + t[l + 4];
        h[hh] = (u2[0] + u2[2]) + (u2[1] + u2[3]);
    }
    dst[r] = h[0] + h[1];
}

// ---------------- K0b: convert codebook to bf16, k-chunk-major [8][1024][32] ----------------
__global__ __launch_bounds__(256) void k_cvt(const float* __restrict__ ew,
                                             unsigned short* __restrict__ ebt)
{
    int t = blockIdx.x * 256 + threadIdx.x;   // 0..8191
    int code = t >> 3, kc = t & 7;
    const float4* src = (const float4*)&ew[(size_t)code * 256 + kc * 32];
    unsigned short* dst = &ebt[((size_t)kc * 1024 + code) * 32];
#pragma unroll
    for (int j = 0; j < 8; ++j) {
        float4 v = src[j];
        ushort4 o;
        o.x = f2b(v.x); o.y = f2b(v.y); o.z = f2b(v.z); o.w = f2b(v.w);
        *(ushort4*)&dst[j * 4] = o;
    }
}

// ---------------- K1: MFMA bf16 screen: per-row min + candidate collection ----------------
// Block: 512 thr (8 waves: wm=w>>2 in 0..1, wn=w&3 in 0..3). 64 rows x 1024 codes
// (4 ct-tiles of 256). Wave tile: 32 rows x 64 codes -> acc[2][4] f32x4.
// A-frag: x[16 rows (l&15)][k=(l>>4)*8+i]; B-frag: e[col (l&15)][same k] (row-major e).
// C/D: col=l&15, row=(l>>4)*4+reg  [m89-verified].
// Candidates: s = sqe[c] - 2*dot_bf16; collect c with s <= rowmin_ct + EPS.
__global__ __launch_bounds__(512) void k_screen(
    const float* __restrict__ x, const unsigned short* __restrict__ ebt,
    const float* __restrict__ sqe,
    int* __restrict__ cnt, int* __restrict__ cand)
{
    __shared__ unsigned short xs[64][264];   // bf16, full K, pad 264 (2-way banks)
    __shared__ unsigned short es[256][56];   // bf16, 32-k chunk, pad 56
    __shared__ float red[64][4];
    __shared__ int lcnt[64];

    const int tid = threadIdx.x;
    const int w = tid >> 6, l = tid & 63;
    const int wm = w >> 2, wn = w & 3;
    const int row0 = blockIdx.x * 64;

    if (tid < 64) lcnt[tid] = 0;

    // stage x tile once: 64 rows x 256 k, f32 -> bf16
    {
        const int row = tid >> 3, kq8 = tid & 7;
        const float4* src = (const float4*)&x[(size_t)(row0 + row) * 256 + kq8 * 32];
#pragma unroll
        for (int j = 0; j < 8; ++j) {
            float4 v = src[j];
            ushort4 o;
            o.x = f2b(v.x); o.y = f2b(v.y); o.z = f2b(v.z); o.w = f2b(v.w);
            *(ushort4*)&xs[row][kq8 * 32 + j * 4] = o;
        }
    }

#pragma unroll 1
    for (int ct = 0; ct < 4; ++ct) {
        f32x4 acc[2][4];
#pragma unroll
        for (int mt = 0; mt < 2; ++mt)
#pragma unroll
            for (int nt = 0; nt < 4; ++nt) acc[mt][nt] = (f32x4)0.f;

#pragma unroll 1
        for (int kc = 0; kc < 8; ++kc) {
            __syncthreads();   // protect es (and xs on first pass) before rewrite
            // stage e chunk: 256 codes x 32 k bf16 = 8192 ushorts; 16 ushorts/thread
            {
                const int cc = tid >> 1, part = tid & 1;
                const unsigned short* s =
                    &ebt[((size_t)kc * 1024 + ct * 256 + cc) * 32 + part * 16];
                *(ushort8*)&es[cc][part * 16 + 0] = *(const ushort8*)&s[0];
                *(ushort8*)&es[cc][part * 16 + 8] = *(const ushort8*)&s[8];
            }
            __syncthreads();
            short8 a[2], b[4];
#pragma unroll
            for (int mt = 0; mt < 2; ++mt)
                a[mt] = *(const short8*)&xs[wm * 32 + mt * 16 + (l & 15)][kc * 32 + (l >> 4) * 8];
#pragma unroll
            for (int nt = 0; nt < 4; ++nt)
                b[nt] = *(const short8*)&es[wn * 64 + nt * 16 + (l & 15)][(l >> 4) * 8];
#pragma unroll
            for (int mt = 0; mt < 2; ++mt)
#pragma unroll
                for (int nt = 0; nt < 4; ++nt)
                    acc[mt][nt] = __builtin_amdgcn_mfma_f32_16x16x32_bf16(
                        a[mt], b[nt], acc[mt][nt], 0, 0, 0);
        }

        // epilogue: s = sqe - 2*dot; per-row min across wave, then across wn-waves
        float sev[4];
#pragma unroll
        for (int nt = 0; nt < 4; ++nt)
            sev[nt] = sqe[ct * 256 + wn * 64 + nt * 16 + (l & 15)];

#pragma unroll
        for (int mt = 0; mt < 2; ++mt)
#pragma unroll
            for (int q = 0; q < 4; ++q) {
                const int rw = wm * 32 + mt * 16 + (l >> 4) * 4 + q;
                float v = 3.4e38f;
#pragma unroll
                for (int nt = 0; nt < 4; ++nt)
                    v = fminf(v, sev[nt] - 2.0f * acc[mt][nt][q]);
#pragma unroll
                for (int m = 1; m < 16; m <<= 1) v = fminf(v, __shfl_xor(v, m));
                if ((l & 15) == 0) red[rw][wn] = v;
            }
        __syncthreads();
#pragma unroll
        for (int mt = 0; mt < 2; ++mt)
#pragma unroll
            for (int q = 0; q < 4; ++q) {
                const int rw = wm * 32 + mt * 16 + (l >> 4) * 4 + q;
                const float rm = fminf(fminf(red[rw][0], red[rw][1]),
                                       fminf(red[rw][2], red[rw][3])) + EPS;
#pragma unroll
                for (int nt = 0; nt < 4; ++nt) {
                    float s = sev[nt] - 2.0f * acc[mt][nt][q];
                    if (s <= rm) {
                        int slot = atomicAdd(&lcnt[rw], 1);
                        if (slot < CAP)
                            cand[(size_t)(row0 + rw) * CAP + slot] =
                                ct * 256 + wn * 64 + nt * 16 + (l & 15);
                    }
                }
            }
        __syncthreads();
    }
    if (tid < 64) cnt[row0 + tid] = lcnt[tid];
}

// ---------------- K1b: exact rescore of candidates (reference-exact chain) ----------------
__global__ __launch_bounds__(256) void k_rescore(
    const float* __restrict__ x, const float* __restrict__ ew,
    const float* __restrict__ sqx, const float* __restrict__ sqe,
    const int* __restrict__ cnt, const int* __restrict__ cand,
    int* __restrict__ idx_out, float* __restrict__ idxf_out, int* __restrict__ hist)
{
#pragma clang fp contract(off)
    const int tid = threadIdx.x;
    const int row = blockIdx.x * 4 + (tid >> 6);
    const int l = tid & 63;
    int n = cnt[row];
    if (n == 1) {
        if (l == 0) {
            int c = cand[(size_t)row * CAP];
            idx_out[row] = c;
            idxf_out[row] = (float)c;
            atomicAdd(&hist[c], 1);
        }
        return;
    }
    if (n == 0) n = CAP + 1;   // defensive: force full scan
    const float sxr = sqx[row];
    const float4* xr = (const float4*)&x[(size_t)row * 256];
    float bestd = 3.4e38f; int bestc = 0x7fffffff;
    if (n <= CAP) {
        if (l < n) {
            const int c = cand[(size_t)row * CAP + l];
            const float4* er = (const float4*)&ew[(size_t)c * 256];
            float acc = 0.f;
#pragma unroll 4
            for (int kq = 0; kq < 64; ++kq) {
                float4 a = xr[kq], b = er[kq];
                acc = __builtin_fmaf(a.x, b.x, acc);
                acc = __builtin_fmaf(a.y, b.y, acc);
                acc = __builtin_fmaf(a.z, b.z, acc);
                acc = __builtin_fmaf(a.w, b.w, acc);
            }
            bestd = (sxr - 2.0f * acc) + sqe[c];
            bestc = c;
        }
    } else {
        for (int base = 0; base < K; base += 64) {
            const int c = base + l;
            const float4* er = (const float4*)&ew[(size_t)c * 256];
            float acc = 0.f;
#pragma unroll 4
            for (int kq = 0; kq < 64; ++kq) {
                float4 a = xr[kq], b = er[kq];
                acc = __builtin_fmaf(a.x, b.x, acc);
                acc = __builtin_fmaf(a.y, b.y, acc);
                acc = __builtin_fmaf(a.z, b.z, acc);
                acc = __builtin_fmaf(a.w, b.w, acc);
            }
            float d = (sxr - 2.0f * acc) + sqe[c];
            if (d < bestd || (d == bestd && c < bestc)) { bestd = d; bestc = c; }
        }
    }
#pragma unroll
    for (int m = 1; m < 64; m <<= 1) {
        float od = __shfl_xor(bestd, m);
        int   oc = __shfl_xor(bestc, m);
        if (od < bestd || (od == bestd && oc < bestc)) { bestd = od; bestc = oc; }
    }
    if (l == 0) {
        idx_out[row] = bestc;
        idxf_out[row] = (float)bestc;
        atomicAdd(&hist[bestc], 1);
    }
}

// ---------------- K2: prefix sum of histogram -> offsets + cursors ----------------
__global__ __launch_bounds__(1024) void k_prefix(
    const int* __restrict__ hist, int* __restrict__ offs, int* __restrict__ curs)
{
    __shared__ int tmp[1024];
    const int tid = threadIdx.x;
    const int h = hist[tid];
    tmp[tid] = h;
    __syncthreads();
    for (int off = 1; off < 1024; off <<= 1) {
        int v = (tid >= off) ? tmp[tid - off] : 0;
        __syncthreads();
        tmp[tid] += v;
        __syncthreads();
    }
    int ex = tmp[tid] - h;
    offs[tid] = ex;
    curs[tid] = ex;
}

// ---------------- K3: fill row-id bins ----------------
__global__ __launch_bounds__(256) void k_fill(
    const int* __restrict__ idx_in, int* __restrict__ curs, int* __restrict__ rowids)
{
    int r = blockIdx.x * 256 + threadIdx.x;
    int c = idx_in[r];
    int slot = atomicAdd(&curs[c], 1);
    rowids[slot] = r;
}

// ---------------- K4: per-code dw + quantized gather-write + loss ----------------
__global__ __launch_bounds__(256) void k_dw(
    const float* __restrict__ x, const float* __restrict__ ew,
    const int* __restrict__ hist, const int* __restrict__ offs,
    const int* __restrict__ rowids,
    float* __restrict__ q_out, float* __restrict__ dw, double* __restrict__ lossp)
{
    const int c = blockIdx.x;
    const int tid = threadIdx.x;
    const int n = hist[c];
    const int base = offs[c];
    const float ev = ew[(size_t)c * 256 + tid];
    float acc = 0.f;
    float lsum = 0.f;
    for (int i = 0; i < n; ++i) {
        int row = rowids[base + i];
        float xv = x[(size_t)row * 256 + tid];
        q_out[(size_t)row * 256 + tid] = ev;
        acc += xv;
        float df = ev - xv;
        lsum += df * df;
    }
    dw[(size_t)c * 256 + tid] = acc;
    const int lane = tid & 63, wid = tid >> 6;
    __shared__ float wsum[4];
#pragma unroll
    for (int m = 1; m < 64; m <<= 1) lsum += __shfl_xor(lsum, m);
    if (lane == 0) wsum[wid] = lsum;
    __syncthreads();
    if (tid == 0)
        lossp[c] = (double)wsum[0] + wsum[1] + wsum[2] + wsum[3];
}

// ---------------- K5: finalize new_cs (+ n) and loss ----------------
__global__ __launch_bounds__(1024) void k_finalize(
    const float* __restrict__ ema_cs, const int* __restrict__ hist,
    const double* __restrict__ lossp, float* __restrict__ out)
{
    __shared__ double red[1024];
    const int tid = threadIdx.x;
    float raw = ema_cs[tid] * 0.99f + 0.01f * (float)hist[tid];
    red[tid] = (double)raw;
    __syncthreads();
    for (int s = 512; s > 0; s >>= 1) {
        if (tid < s) red[tid] += red[tid + s];
        __syncthreads();
    }
    double n = red[0];
    __syncthreads();
    float csn = (raw + 1e-5f) * (float)(n / (n + 1024.0 * 1e-5));
    out[OFF_CS + tid] = csn;
    red[tid] = lossp[tid];
    __syncthreads();
    for (int s = 512; s > 0; s >>= 1) {
        if (tid < s) red[tid] += red[tid + s];
        __syncthreads();
    }
    if (tid == 0) out[OFF_LOSS] = (float)(red[0] * 1.25 / 16777216.0);
}

// ---------------- K6: new_ema_w + updated_embed ----------------
__global__ __launch_bounds__(256) void k_ema(
    const float* __restrict__ ema_w, const float* __restrict__ dw,
    const float* __restrict__ cs_out, float* __restrict__ out)
{
    int id = blockIdx.x * 256 + threadIdx.x;
    int k = id >> 8;
    float nw = ema_w[id] * 0.99f + 0.01f * dw[id];
    out[OFF_EMAW + id] = nw;
    out[OFF_UPD + id] = nw / cs_out[k];
}

extern "C" void kernel_launch(void* const* d_in, const int* in_sizes, int n_in,
                              void* d_out, int out_size, void* d_ws, size_t ws_size,
                              hipStream_t stream)
{
    const float* x      = (const float*)d_in[0];
    const float* ew     = (const float*)d_in[1];
    const float* ema_cs = (const float*)d_in[2];
    const float* ema_w  = (const float*)d_in[3];
    float* out = (float*)d_out;
    char* ws = (char*)d_ws;

    int*    hist    = (int*)(ws + WS_HIST);
    int*    cnt     = (int*)(ws + WS_CNT);
    int*    offs    = (int*)(ws + WS_OFFS);
    int*    curs    = (int*)(ws + WS_CURS);
    int*    idxi    = (int*)(ws + WS_IDX);
    int*    rowids  = (int*)(ws + WS_ROWIDS);
    float*  sqx     = (float*)(ws + WS_SQX);
    float*  sqe     = (float*)(ws + WS_SQE);
    float*  dw      = (float*)(ws + WS_DW);
    double* lossp   = (double*)(ws + WS_LOSSP);
    unsigned short* ebt = (unsigned short*)(ws + WS_EBT);
    int*    cand    = (int*)(ws + WS_CAND);

    hipMemsetAsync(ws, 0, WS_OFFS, stream);   // hist + cnt
    hipLaunchKernelGGL(k_sq, dim3(NROWS / 256), dim3(256), 0, stream, x, sqx, NROWS);
    hipLaunchKernelGGL(k_sq, dim3(K / 256), dim3(256), 0, stream, ew, sqe, K);
    hipLaunchKernelGGL(k_cvt, dim3(32), dim3(256), 0, stream, ew, ebt);
    hipLaunchKernelGGL(k_screen, dim3(NROWS / 64), dim3(512), 0, stream,
                       x, ebt, sqe, cnt, cand);
    hipLaunchKernelGGL(k_rescore, dim3(NROWS / 4), dim3(256), 0, stream,
                       x, ew, sqx, sqe, cnt, cand, idxi, out + OFF_IDX, hist);
    hipLaunchKernelGGL(k_prefix, dim3(1), dim3(1024), 0, stream, hist, offs, curs);
    hipLaunchKernelGGL(k_fill, dim3(NROWS / 256), dim3(256), 0, stream,
                       idxi, curs, rowids);
    hipLaunchKernelGGL(k_dw, dim3(K), dim3(256), 0, stream,
                       x, ew, hist, offs, rowids, out + OFF_Q, dw, lossp);
    hipLaunchKernelGGL(k_finalize, dim3(1), dim3(1024), 0, stream,
                       ema_cs, hist, lossp, out);
    hipLaunchKernelGGL(k_ema, dim3(1024), dim3(256), 0, stream,
                       ema_w, dw, out + OFF_CS, out);
}

// Round 10
// 328.850 us; speedup vs baseline: 1.6313x; 1.3776x over previous
//
#include <hip/hip_runtime.h>
#include <math.h>

#define NROWS 65536
#define D 256
#define K 1024
#define CAP 16
#define EPS 2e-3f

// d_out offsets (floats)
#define OFF_Q     0
#define OFF_LOSS  16777216
#define OFF_IDX   16777217
#define OFF_CS    16842753
#define OFF_EMAW  16843777
#define OFF_UPD   17105921

// ws offsets (bytes)
#define WS_HIST     0          // 1024 int   (memset 0)
#define WS_CNT      4096       // 65536 int
#define WS_OFFS     266240     // 1024 int
#define WS_CURS     270336     // 1024 int
#define WS_IDX      274432     // 65536 int
#define WS_ROWIDS   536576     // 65536 int (k_fill output; aliased as wrows earlier)
#define WS_WROWS    536576     //   alias: worklist rows (dead before k_fill runs)
#define WS_SQX      798720     // 65536 f32
#define WS_SQE      1060864    // 1024 f32
#define WS_DW       1064960    // 262144 f32 (k_dw output; aliased as packed earlier)
#define WS_PACK     1064960    //   alias: 65536 u64 (memset 0xFF; dead before k_dw)
#define WS_GCNT     1589264    //   alias: 1 int inside WS_DW region (memset 0)
#define WS_LOSSP    2113536    // 1024 double
#define WS_EBT      2121728    // 8*1024*32 ushort (bf16, k-chunk-major)
#define WS_CAND     2646016    // 65536*16 int  (ends 6840320)

typedef __attribute__((ext_vector_type(8))) short short8;
typedef __attribute__((ext_vector_type(8))) unsigned short ushort8;
typedef __attribute__((ext_vector_type(4))) float f32x4;

__device__ __forceinline__ unsigned short f2b(float f) {   // RNE f32->bf16
    unsigned u = __builtin_bit_cast(unsigned, f);
    return (unsigned short)((u + 0x7fffu + ((u >> 16) & 1u)) >> 16);
}

// exact reference-order dot: single f32 acc, fmaf over k=0..255 ascending.
// 8 float4-pairs loaded per group (16 loads in flight) to hide latency.
__device__ __forceinline__ float dot_chain(const float4* __restrict__ xr,
                                           const float4* __restrict__ er) {
#pragma clang fp contract(off)
    float acc = 0.f;
#pragma unroll
    for (int g = 0; g < 8; ++g) {
        float4 xa[8], ea[8];
#pragma unroll
        for (int m = 0; m < 8; ++m) { xa[m] = xr[g * 8 + m]; ea[m] = er[g * 8 + m]; }
#pragma unroll
        for (int m = 0; m < 8; ++m) {
            acc = __builtin_fmaf(xa[m].x, ea[m].x, acc);
            acc = __builtin_fmaf(xa[m].y, ea[m].y, acc);
            acc = __builtin_fmaf(xa[m].z, ea[m].z, acc);
            acc = __builtin_fmaf(xa[m].w, ea[m].w, acc);
        }
    }
    return acc;
}

// ---------------- K0: row sum-of-squares, numpy AVX512 pairwise order ----------------
__global__ __launch_bounds__(256) void k_sq(const float* __restrict__ a_,
                                            float* __restrict__ dst, int n)
{
#pragma clang fp contract(off)
    int r = blockIdx.x * 256 + threadIdx.x;
    if (r >= n) return;
    const float4* a4 = (const float4*)(a_ + (size_t)r * 256);
    float h[2];
#pragma unroll
    for (int hh = 0; hh < 2; ++hh) {
        float p[4][16];
#pragma unroll
        for (int pr = 0; pr < 4; ++pr) {
#pragma unroll
            for (int m = 0; m < 4; ++m) {
                float4 u = a4[hh * 32 + (2 * pr) * 4 + m];
                float4 v = a4[hh * 32 + (2 * pr + 1) * 4 + m];
                p[pr][4 * m + 0] = u.x * u.x + v.x * v.x;
                p[pr][4 * m + 1] = u.y * u.y + v.y * v.y;
                p[pr][4 * m + 2] = u.z * u.z + v.z * v.z;
                p[pr][4 * m + 3] = u.w * u.w + v.w * v.w;
            }
        }
        float V[16];
#pragma unroll
        for (int l = 0; l < 16; ++l) V[l] = (p[0][l] + p[1][l]) + (p[2][l] + p[3][l]);
        float t[8];
#pragma unroll
        for (int l = 0; l < 8; ++l) t[l] = V[l] + V[l + 8];
        float u2[4];
#pragma unroll
        for (int l = 0; l < 4; ++l) u2[l] = t[l] + t[l + 4];
        h[hh] = (u2[0] + u2[2]) + (u2[1] + u2[3]);
    }
    dst[r] = h[0] + h[1];
}

// ---------------- K0b: convert codebook to bf16, k-chunk-major [8][1024][32] ----------------
__global__ __launch_bounds__(256) void k_cvt(const float* __restrict__ ew,
                                             unsigned short* __restrict__ ebt)
{
    int t = blockIdx.x * 256 + threadIdx.x;   // 0..8191
    int code = t >> 3, kc = t & 7;
    const float4* src = (const float4*)&ew[(size_t)code * 256 + kc * 32];
    unsigned short* dst = &ebt[((size_t)kc * 1024 + code) * 32];
#pragma unroll
    for (int j = 0; j < 8; ++j) {
        float4 v = src[j];
        ushort4 o;
        o.x = f2b(v.x); o.y = f2b(v.y); o.z = f2b(v.z); o.w = f2b(v.w);
        *(ushort4*)&dst[j * 4] = o;
    }
}

// ---------------- K1: MFMA bf16 screen + n==1 fast path + worklist ----------------
__global__ __launch_bounds__(512) void k_screen(
    const float* __restrict__ x, const unsigned short* __restrict__ ebt,
    const float* __restrict__ sqe,
    int* __restrict__ cnt, int* __restrict__ cand,
    int* __restrict__ idx_out, float* __restrict__ idxf_out,
    int* __restrict__ hist, int* __restrict__ wrows, int* __restrict__ gcount)
{
    __shared__ unsigned short xs[64][264];   // bf16, full K
    __shared__ unsigned short es[256][56];   // bf16, 32-k chunk
    __shared__ float red[64][4];
    __shared__ int lcnt[64];
    __shared__ int scand[64];

    const int tid = threadIdx.x;
    const int w = tid >> 6, l = tid & 63;
    const int wm = w >> 2, wn = w & 3;
    const int row0 = blockIdx.x * 64;

    if (tid < 64) lcnt[tid] = 0;

    // stage x tile once: 64 rows x 256 k, f32 -> bf16
    {
        const int row = tid >> 3, kq8 = tid & 7;
        const float4* src = (const float4*)&x[(size_t)(row0 + row) * 256 + kq8 * 32];
#pragma unroll
        for (int j = 0; j < 8; ++j) {
            float4 v = src[j];
            ushort4 o;
            o.x = f2b(v.x); o.y = f2b(v.y); o.z = f2b(v.z); o.w = f2b(v.w);
            *(ushort4*)&xs[row][kq8 * 32 + j * 4] = o;
        }
    }

#pragma unroll 1
    for (int ct = 0; ct < 4; ++ct) {
        f32x4 acc[2][4];
#pragma unroll
        for (int mt = 0; mt < 2; ++mt)
#pragma unroll
            for (int nt = 0; nt < 4; ++nt) acc[mt][nt] = (f32x4)0.f;

#pragma unroll 1
        for (int kc = 0; kc < 8; ++kc) {
            __syncthreads();
            // stage e chunk: 256 codes x 32 k bf16 = 8192 ushorts; 16/thread
            {
                const int cc = tid >> 1, part = tid & 1;
                const unsigned short* s =
                    &ebt[((size_t)kc * 1024 + ct * 256 + cc) * 32 + part * 16];
                *(ushort8*)&es[cc][part * 16 + 0] = *(const ushort8*)&s[0];
                *(ushort8*)&es[cc][part * 16 + 8] = *(const ushort8*)&s[8];
            }
            __syncthreads();
            short8 a[2], b[4];
#pragma unroll
            for (int mt = 0; mt < 2; ++mt)
                a[mt] = *(const short8*)&xs[wm * 32 + mt * 16 + (l & 15)][kc * 32 + (l >> 4) * 8];
#pragma unroll
            for (int nt = 0; nt < 4; ++nt)
                b[nt] = *(const short8*)&es[wn * 64 + nt * 16 + (l & 15)][(l >> 4) * 8];
#pragma unroll
            for (int mt = 0; mt < 2; ++mt)
#pragma unroll
                for (int nt = 0; nt < 4; ++nt)
                    acc[mt][nt] = __builtin_amdgcn_mfma_f32_16x16x32_bf16(
                        a[mt], b[nt], acc[mt][nt], 0, 0, 0);
        }

        float sev[4];
#pragma unroll
        for (int nt = 0; nt < 4; ++nt)
            sev[nt] = sqe[ct * 256 + wn * 64 + nt * 16 + (l & 15)];

#pragma unroll
        for (int mt = 0; mt < 2; ++mt)
#pragma unroll
            for (int q = 0; q < 4; ++q) {
                const int rw = wm * 32 + mt * 16 + (l >> 4) * 4 + q;
                float v = 3.4e38f;
#pragma unroll
                for (int nt = 0; nt < 4; ++nt)
                    v = fminf(v, sev[nt] - 2.0f * acc[mt][nt][q]);
#pragma unroll
                for (int m = 1; m < 16; m <<= 1) v = fminf(v, __shfl_xor(v, m));
                if ((l & 15) == 0) red[rw][wn] = v;
            }
        __syncthreads();
#pragma unroll
        for (int mt = 0; mt < 2; ++mt)
#pragma unroll
            for (int q = 0; q < 4; ++q) {
                const int rw = wm * 32 + mt * 16 + (l >> 4) * 4 + q;
                const float rm = fminf(fminf(red[rw][0], red[rw][1]),
                                       fminf(red[rw][2], red[rw][3])) + EPS;
#pragma unroll
                for (int nt = 0; nt < 4; ++nt) {
                    float s = sev[nt] - 2.0f * acc[mt][nt][q];
                    if (s <= rm) {
                        int c = ct * 256 + wn * 64 + nt * 16 + (l & 15);
                        int slot = atomicAdd(&lcnt[rw], 1);
                        if (slot == 0) scand[rw] = c;
                        if (slot < CAP)
                            cand[(size_t)(row0 + rw) * CAP + slot] = c;
                    }
                }
            }
        __syncthreads();
    }
    if (tid < 64) {
        const int row = row0 + tid;
        const int n = lcnt[tid];
        cnt[row] = n;
        if (n == 1) {
            const int c = scand[tid];
            idx_out[row] = c;
            idxf_out[row] = (float)c;
            atomicAdd(&hist[c], 1);
        } else {
            int p = atomicAdd(gcount, 1);
            wrows[p] = row;
        }
    }
}

// ---------------- K1b: pair-per-lane exact rescore -> packed atomicMin ----------------
__global__ __launch_bounds__(256) void k_rescore(
    const float* __restrict__ x, const float* __restrict__ ew,
    const float* __restrict__ sqx, const float* __restrict__ sqe,
    const int* __restrict__ cnt, const int* __restrict__ cand,
    const int* __restrict__ wrows, const int* __restrict__ gcount,
    unsigned long long* __restrict__ packed)
{
#pragma clang fp contract(off)
    const int nw = *gcount;
    const int total = nw * CAP;
    for (int i = blockIdx.x * 256 + threadIdx.x; i < total; i += gridDim.x * 256) {
        const int row = wrows[i >> 4];
        const int slot = i & (CAP - 1);
        const int n = cnt[row];
        const float sxr = sqx[row];
        const float4* xr = (const float4*)&x[(size_t)row * 256];
        if (n <= CAP) {
            if (slot >= n) continue;
            const int c = cand[(size_t)row * CAP + slot];
            float acc = dot_chain(xr, (const float4*)&ew[(size_t)c * 256]);
            float d = (sxr - 2.0f * acc) + sqe[c];
            unsigned long long key =
                ((unsigned long long)__builtin_bit_cast(unsigned, d) << 32) | (unsigned)c;
            atomicMin(&packed[row], key);
        } else {
            // overflow fallback (essentially never): strided exact full scan
            float bd = 3.4e38f; int bc = 0x7fffffff;
            for (int c = slot; c < K; c += CAP) {
                float acc = dot_chain(xr, (const float4*)&ew[(size_t)c * 256]);
                float d = (sxr - 2.0f * acc) + sqe[c];
                if (d < bd || (d == bd && c < bc)) { bd = d; bc = c; }
            }
            unsigned long long key =
                ((unsigned long long)__builtin_bit_cast(unsigned, bd) << 32) | (unsigned)bc;
            atomicMin(&packed[row], key);
        }
    }
}

// ---------------- K1c: resolve worklist rows -> idx + hist ----------------
__global__ __launch_bounds__(256) void k_resolve(
    const int* __restrict__ wrows, const int* __restrict__ gcount,
    const unsigned long long* __restrict__ packed,
    int* __restrict__ idx_out, float* __restrict__ idxf_out, int* __restrict__ hist)
{
    const int nw = *gcount;
    for (int i = blockIdx.x * 256 + threadIdx.x; i < nw; i += gridDim.x * 256) {
        const int row = wrows[i];
        const int c = (int)(packed[row] & 0xffffffffu);
        idx_out[row] = c;
        idxf_out[row] = (float)c;
        atomicAdd(&hist[c], 1);
    }
}

// ---------------- K2: prefix sum of histogram -> offsets + cursors ----------------
__global__ __launch_bounds__(1024) void k_prefix(
    const int* __restrict__ hist, int* __restrict__ offs, int* __restrict__ curs)
{
    __shared__ int tmp[1024];
    const int tid = threadIdx.x;
    const int h = hist[tid];
    tmp[tid] = h;
    __syncthreads();
    for (int off = 1; off < 1024; off <<= 1) {
        int v = (tid >= off) ? tmp[tid - off] : 0;
        __syncthreads();
        tmp[tid] += v;
        __syncthreads();
    }
    int ex = tmp[tid] - h;
    offs[tid] = ex;
    curs[tid] = ex;
}

// ---------------- K3: fill row-id bins ----------------
__global__ __launch_bounds__(256) void k_fill(
    const int* __restrict__ idx_in, int* __restrict__ curs, int* __restrict__ rowids)
{
    int r = blockIdx.x * 256 + threadIdx.x;
    int c = idx_in[r];
    int slot = atomicAdd(&curs[c], 1);
    rowids[slot] = r;
}

// ---------------- K4: per-code dw + quantized gather-write + loss ----------------
__global__ __launch_bounds__(256) void k_dw(
    const float* __restrict__ x, const float* __restrict__ ew,
    const int* __restrict__ hist, const int* __restrict__ offs,
    const int* __restrict__ rowids,
    float* __restrict__ q_out, float* __restrict__ dw, double* __restrict__ lossp)
{
    const int c = blockIdx.x;
    const int tid = threadIdx.x;
    const int n = hist[c];
    const int base = offs[c];
    const float ev = ew[(size_t)c * 256 + tid];
    float acc = 0.f;
    float lsum = 0.f;
    for (int i = 0; i < n; ++i) {
        int row = rowids[base + i];
        float xv = x[(size_t)row * 256 + tid];
        q_out[(size_t)row * 256 + tid] = ev;
        acc += xv;
        float df = ev - xv;
        lsum += df * df;
    }
    dw[(size_t)c * 256 + tid] = acc;
    const int lane = tid & 63, wid = tid >> 6;
    __shared__ float wsum[4];
#pragma unroll
    for (int m = 1; m < 64; m <<= 1) lsum += __shfl_xor(lsum, m);
    if (lane == 0) wsum[wid] = lsum;
    __syncthreads();
    if (tid == 0)
        lossp[c] = (double)wsum[0] + wsum[1] + wsum[2] + wsum[3];
}

// ---------------- K5: finalize new_cs (+ n) and loss ----------------
__global__ __launch_bounds__(1024) void k_finalize(
    const float* __restrict__ ema_cs, const int* __restrict__ hist,
    const double* __restrict__ lossp, float* __restrict__ out)
{
    __shared__ double red[1024];
    const int tid = threadIdx.x;
    float raw = ema_cs[tid] * 0.99f + 0.01f * (float)hist[tid];
    red[tid] = (double)raw;
    __syncthreads();
    for (int s = 512; s > 0; s >>= 1) {
        if (tid < s) red[tid] += red[tid + s];
        __syncthreads();
    }
    double n = red[0];
    __syncthreads();
    float csn = (raw + 1e-5f) * (float)(n / (n + 1024.0 * 1e-5));
    out[OFF_CS + tid] = csn;
    red[tid] = lossp[tid];
    __syncthreads();
    for (int s = 512; s > 0; s >>= 1) {
        if (tid < s) red[tid] += red[tid + s];
        __syncthreads();
    }
    if (tid == 0) out[OFF_LOSS] = (float)(red[0] * 1.25 / 16777216.0);
}

// ---------------- K6: new_ema_w + updated_embed ----------------
__global__ __launch_bounds__(256) void k_ema(
    const float* __restrict__ ema_w, const float* __restrict__ dw,
    const float* __restrict__ cs_out, float* __restrict__ out)
{
    int id = blockIdx.x * 256 + threadIdx.x;
    int k = id >> 8;
    float nw = ema_w[id] * 0.99f + 0.01f * dw[id];
    out[OFF_EMAW + id] = nw;
    out[OFF_UPD + id] = nw / cs_out[k];
}

extern "C" void kernel_launch(void* const* d_in, const int* in_sizes, int n_in,
                              void* d_out, int out_size, void* d_ws, size_t ws_size,
                              hipStream_t stream)
{
    const float* x      = (const float*)d_in[0];
    const float* ew     = (const float*)d_in[1];
    const float* ema_cs = (const float*)d_in[2];
    const float* ema_w  = (const float*)d_in[3];
    float* out = (float*)d_out;
    char* ws = (char*)d_ws;

    int*    hist    = (int*)(ws + WS_HIST);
    int*    cnt     = (int*)(ws + WS_CNT);
    int*    offs    = (int*)(ws + WS_OFFS);
    int*    curs    = (int*)(ws + WS_CURS);
    int*    idxi    = (int*)(ws + WS_IDX);
    int*    rowids  = (int*)(ws + WS_ROWIDS);
    int*    wrows   = (int*)(ws + WS_WROWS);
    float*  sqx     = (float*)(ws + WS_SQX);
    float*  sqe     = (float*)(ws + WS_SQE);
    float*  dw      = (float*)(ws + WS_DW);
    unsigned long long* packed = (unsigned long long*)(ws + WS_PACK);
    int*    gcnt    = (int*)(ws + WS_GCNT);
    double* lossp   = (double*)(ws + WS_LOSSP);
    unsigned short* ebt = (unsigned short*)(ws + WS_EBT);
    int*    cand    = (int*)(ws + WS_CAND);

    hipMemsetAsync(hist, 0, 4096, stream);
    hipMemsetAsync(packed, 0xFF, 524288, stream);
    hipMemsetAsync(gcnt, 0, 16, stream);
    hipLaunchKernelGGL(k_sq, dim3(NROWS / 256), dim3(256), 0, stream, x, sqx, NROWS);
    hipLaunchKernelGGL(k_sq, dim3(K / 256), dim3(256), 0, stream, ew, sqe, K);
    hipLaunchKernelGGL(k_cvt, dim3(32), dim3(256), 0, stream, ew, ebt);
    hipLaunchKernelGGL(k_screen, dim3(NROWS / 64), dim3(512), 0, stream,
                       x, ebt, sqe, cnt, cand, idxi, out + OFF_IDX, hist, wrows, gcnt);
    hipLaunchKernelGGL(k_rescore, dim3(1024), dim3(256), 0, stream,
                       x, ew, sqx, sqe, cnt, cand, wrows, gcnt, packed);
    hipLaunchKernelGGL(k_resolve, dim3(64), dim3(256), 0, stream,
                       wrows, gcnt, packed, idxi, out + OFF_IDX, hist);
    hipLaunchKernelGGL(k_prefix, dim3(1), dim3(1024), 0, stream, hist, offs, curs);
    hipLaunchKernelGGL(k_fill, dim3(NROWS / 256), dim3(256), 0, stream,
                       idxi, curs, rowids);
    hipLaunchKernelGGL(k_dw, dim3(K), dim3(256), 0, stream,
                       x, ew, hist, offs, rowids, out + OFF_Q, dw, lossp);
    hipLaunchKernelGGL(k_finalize, dim3(1), dim3(1024), 0, stream,
                       ema_cs, hist, lossp, out);
    hipLaunchKernelGGL(k_ema, dim3(1024), dim3(256), 0, stream,
                       ema_w, dw, out + OFF_CS, out);
}